// Round 25
// baseline (199.883 us; speedup 1.0000x reference)
//
#include <hip/hip_runtime.h>
#include <stdint.h>

typedef unsigned short u16;
typedef unsigned int u32;
typedef __bf16 bf16x8 __attribute__((ext_vector_type(8)));
typedef float f32x4 __attribute__((ext_vector_type(4)));
typedef u32 u32x4 __attribute__((ext_vector_type(4)));

__device__ __forceinline__ u16 f2bf(float x){
  u32 u = __float_as_uint(x);
  u += 0x7FFFu + ((u >> 16) & 1u);
  return (u16)(u >> 16);
}
__device__ __forceinline__ float bf2f(u16 h){
  return __uint_as_float(((u32)h) << 16);
}
__device__ __forceinline__ u32 cvt_pk_bf16(float lo, float hi){
  u32 r;
  asm("v_cvt_pk_bf16_f32 %0, %1, %2" : "=v"(r) : "v"(lo), "v"(hi));
  return r;
}
__device__ __forceinline__ f32x4 mfma16(bf16x8 a, bf16x8 b, f32x4 c){
  return __builtin_amdgcn_mfma_f32_16x16x32_bf16(a, b, c, 0, 0, 0);
}
// async global->LDS, 16B per lane. LDS dest = wave-uniform base + lane*16.
__device__ __forceinline__ void gload16(const void* g, const void* l){
  __builtin_amdgcn_global_load_lds(
      (__attribute__((address_space(1))) void*)(uintptr_t)g,
      (__attribute__((address_space(3))) void*)(u32)(uintptr_t)l,
      16, 0, 0);
}

// ---------------- fused prep: cast | trans_qkv | trans_wc | rope_table ----------------
__global__ __launch_bounds__(256) void k_prep(const float* __restrict__ hidden,
    const float* __restrict__ Wq, const float* __restrict__ Wk, const float* __restrict__ Wv,
    const float* __restrict__ Wc, u16* __restrict__ hid_bf, u16* __restrict__ wqkv_t,
    u16* __restrict__ wct, float* __restrict__ ct, float* __restrict__ st){
  __shared__ float tile[32][33];
  int bid = blockIdx.x;
  int t = threadIdx.x;
  if (bid < 8192){                       // f32 -> bf16 cast of hidden
    int i = (bid * 256 + t) * 4;
    float4 v = *(const float4*)(hidden + i);
    ushort4 o;
    o.x = f2bf(v.x); o.y = f2bf(v.y); o.z = f2bf(v.z); o.w = f2bf(v.w);
    *(ushort4*)(hid_bf + i) = o;
    return;
  }
  if (bid < 8192 + 6144){                // Wq|Wk|Wv transpose+cast -> wqkv_t[n][k]
    int b2 = bid - 8192;
    int nb = (b2 % 96) * 32, kb = (b2 / 96) * 32;
    int tx = t & 31, ty = t >> 5;
    #pragma unroll
    for (int j = 0; j < 4; j++){
      int k = kb + ty + j*8;
      int n = nb + tx;
      float v;
      if (n < 2048)      v = Wq[(size_t)k*2048 + n];
      else if (n < 2560) v = Wk[(size_t)k*512 + (n - 2048)];
      else               v = Wv[(size_t)k*512 + (n - 2560)];
      tile[tx][ty + j*8] = v;
    }
    __syncthreads();
    #pragma unroll
    for (int j = 0; j < 4; j++){
      int n = nb + ty + j*8;
      wqkv_t[(size_t)n*2048 + kb + tx] = f2bf(tile[ty + j*8][tx]);
    }
    return;
  }
  if (bid < 8192 + 6144 + 4096){         // Wc transpose+cast -> wct[n][k]
    int b3 = bid - 8192 - 6144;
    int nb = (b3 % 64) * 32, kb = (b3 / 64) * 32;
    int tx = t & 31, ty = t >> 5;
    #pragma unroll
    for (int j = 0; j < 4; j++){
      tile[tx][ty + j*8] = Wc[(size_t)(kb + ty + j*8)*2048 + nb + tx];
    }
    __syncthreads();
    #pragma unroll
    for (int j = 0; j < 4; j++){
      wct[(size_t)(nb + ty + j*8)*2048 + kb + tx] = f2bf(tile[ty + j*8][tx]);
    }
    return;
  }
  {                                      // RoPE cos/sin table
    int b4 = bid - 8192 - 6144 - 4096;
    int idx = b4 * 256 + t;
    int p = idx >> 6, i = idx & 63;
    float freq = powf(10000.0f, -(float)i / 64.0f);
    float ang = (float)p * freq;
    ct[idx] = cosf(ang);
    st[idx] = sinf(ang);
  }
}

// ------- QKV GEMM: q/k column-blocks (bx<20) -> normal bf16 C-write to qkv;
// v column-blocks (bx>=20) -> fused transpose to vt via staging-LDS reuse.
// K is a RUNTIME arg (prevents full K-loop unroll / I$ blowout). -------
__global__ __launch_bounds__(256) void k_gemm_qkv(const u16* __restrict__ A, const u16* __restrict__ Bt,
    u16* __restrict__ qkv, u16* __restrict__ vt, int K){
  __shared__ u16 lds[16384];   // A0|A1|B0|B1 (4 x 4096 u16); V epilogue reuses as 128x128 tile
  int tid = threadIdx.x;
  int lane = tid & 63, w = tid >> 6;
  int g = lane >> 4, c16 = lane & 15;
  int wr = w >> 1, wc = w & 1;
  int chunk = gridDim.x >> 3;
  int logical = (blockIdx.x & 7) * chunk + (blockIdx.x >> 3);
  int bx = logical % 24, by = logical / 24;
  size_t bm = (size_t)by * 128, bn = (size_t)bx * 128;
  f32x4 zero = {0.f, 0.f, 0.f, 0.f};
  f32x4 acc[4][4];
  #pragma unroll
  for (int i=0;i<4;i++)
    #pragma unroll
    for (int j=0;j<4;j++) acc[i][j] = zero;

  int jj = (w*2)*64 + lane;
  const int nt = K >> 5;
  #pragma unroll
  for (int p = 0; p < 2; p++){
    int j = jj + p*64;
    int r = j >> 2, slot = j & 3;
    gload16(A  + (bm + r)*(size_t)K + slot*8, (const char*)(lds)        + (w*2+p)*1024);
    gload16(Bt + (bn + r)*(size_t)K + slot*8, (const char*)(lds + 8192) + (w*2+p)*1024);
  }
  asm volatile("s_waitcnt vmcnt(0)" ::: "memory");
  __builtin_amdgcn_s_barrier();

  int cur = 0;
  #pragma unroll 1
  for (int t = 0; t < nt; ++t){
    if (t + 1 < nt){
      int k0 = (t + 1) << 5;
      #pragma unroll
      for (int p = 0; p < 2; p++){
        int j = jj + p*64;
        int r = j >> 2, slot = j & 3;
        gload16(A  + (bm + r)*(size_t)K + k0 + slot*8, (const char*)(lds + (cur^1)*4096)        + (w*2+p)*1024);
        gload16(Bt + (bn + r)*(size_t)K + k0 + slot*8, (const char*)(lds + 8192 + (cur^1)*4096) + (w*2+p)*1024);
      }
    }
    const u16* Ac = lds + cur*4096;
    const u16* Bc = lds + 8192 + cur*4096;
    bf16x8 af[4], bfr[4];
    #pragma unroll
    for (int mi=0;mi<4;mi++) af[mi]  = *(const bf16x8*)&Ac[(wr*64 + mi*16 + c16)*32 + g*8];
    #pragma unroll
    for (int ni=0;ni<4;ni++) bfr[ni] = *(const bf16x8*)&Bc[(wc*64 + ni*16 + c16)*32 + g*8];
    #pragma unroll
    for (int mi=0;mi<4;mi++)
      #pragma unroll
      for (int ni=0;ni<4;ni++)
        acc[mi][ni] = mfma16(af[mi], bfr[ni], acc[mi][ni]);
    if (t + 1 < nt){
      asm volatile("s_waitcnt vmcnt(0)" ::: "memory");
      __builtin_amdgcn_s_barrier();
    }
    cur ^= 1;
  }
  if (bx < 20){
    // q/k: normal bf16 C-write into qkv[m][3072] (v columns left unwritten/unused)
    #pragma unroll
    for (int mi=0;mi<4;mi++){
      #pragma unroll
      for (int ni=0;ni<4;ni++){
        #pragma unroll
        for (int r=0;r<4;r++){
          size_t row = bm + wr*64 + mi*16 + g*4 + r;
          size_t col = bn + wc*64 + ni*16 + c16;
          qkv[row * (size_t)3072 + col] = f2bf(acc[mi][ni][r]);
        }
      }
    }
  } else {
    // v: transpose via staging-LDS reuse, coalesced 16B stores to vt[b,kvh,d,s]
    __syncthreads();   // all waves done reading staging LDS
    #pragma unroll
    for (int mi=0;mi<4;mi++)
      #pragma unroll
      for (int ni=0;ni<4;ni++)
        #pragma unroll
        for (int r=0;r<4;r++){
          int row = wr*64 + mi*16 + g*4 + r;
          int col = wc*64 + ni*16 + c16;
          lds[col*128 + row] = f2bf(acc[mi][ni][r]);
        }
    __syncthreads();
    int b = (int)(bm >> 11), s0 = (int)(bm & 2047);
    int kvh = bx - 20;
    u16* dst0 = vt + ((size_t)(b*4 + kvh) * 128) * 2048 + s0;
    #pragma unroll
    for (int i = 0; i < 8; i++){
      int ch = i*256 + tid;        // 0..2047: ALL 16B-chunks of the 128x128 tile
      int d = ch >> 4;
      int off = (ch & 15) * 8;
      uint4 vv = *(uint4*)&lds[d*128 + off];
      *(uint4*)(dst0 + (size_t)d*2048 + off) = vv;
    }
  }
}

// ------- generic GEMM (output proj), T3-min 2-phase pipeline -------
template<bool OBF>
__global__ __launch_bounds__(256) void k_gemm(const u16* __restrict__ A, const u16* __restrict__ Bt,
                                              void* __restrict__ Cv, int M, int N, int K, int nbx){
  __shared__ u16 As[2][128*32], Bs[2][128*32];
  int tid = threadIdx.x;
  int lane = tid & 63, w = tid >> 6;
  int g = lane >> 4, c16 = lane & 15;
  int wr = w >> 1, wc = w & 1;
  int chunk = gridDim.x >> 3;
  int logical = (blockIdx.x & 7) * chunk + (blockIdx.x >> 3);
  int bx = logical % nbx, by = logical / nbx;
  size_t bm = (size_t)by * 128, bn = (size_t)bx * 128;
  f32x4 zero = {0.f, 0.f, 0.f, 0.f};
  f32x4 acc[4][4];
  #pragma unroll
  for (int i=0;i<4;i++)
    #pragma unroll
    for (int j=0;j<4;j++) acc[i][j] = zero;

  int jj = (w*2)*64 + lane;
  int nt = K >> 5;
  #pragma unroll
  for (int p = 0; p < 2; p++){
    int j = jj + p*64;
    int r = j >> 2, slot = j & 3;
    gload16(A  + (bm + r)*(size_t)K + slot*8, (const char*)As[0] + (w*2+p)*1024);
    gload16(Bt + (bn + r)*(size_t)K + slot*8, (const char*)Bs[0] + (w*2+p)*1024);
  }
  asm volatile("s_waitcnt vmcnt(0)" ::: "memory");
  __builtin_amdgcn_s_barrier();

  int cur = 0;
  #pragma unroll 1
  for (int t = 0; t < nt; ++t){
    if (t + 1 < nt){
      int k0 = (t + 1) << 5;
      #pragma unroll
      for (int p = 0; p < 2; p++){
        int j = jj + p*64;
        int r = j >> 2, slot = j & 3;
        gload16(A  + (bm + r)*(size_t)K + k0 + slot*8, (const char*)As[cur^1] + (w*2+p)*1024);
        gload16(Bt + (bn + r)*(size_t)K + k0 + slot*8, (const char*)Bs[cur^1] + (w*2+p)*1024);
      }
    }
    const u16* Ac = As[cur];
    const u16* Bc = Bs[cur];
    bf16x8 af[4], bfr[4];
    #pragma unroll
    for (int mi=0;mi<4;mi++) af[mi]  = *(const bf16x8*)&Ac[(wr*64 + mi*16 + c16)*32 + g*8];
    #pragma unroll
    for (int ni=0;ni<4;ni++) bfr[ni] = *(const bf16x8*)&Bc[(wc*64 + ni*16 + c16)*32 + g*8];
    #pragma unroll
    for (int mi=0;mi<4;mi++)
      #pragma unroll
      for (int ni=0;ni<4;ni++)
        acc[mi][ni] = mfma16(af[mi], bfr[ni], acc[mi][ni]);
    if (t + 1 < nt){
      asm volatile("s_waitcnt vmcnt(0)" ::: "memory");
      __builtin_amdgcn_s_barrier();
    }
    cur ^= 1;
  }
  #pragma unroll
  for (int mi=0;mi<4;mi++){
    #pragma unroll
    for (int ni=0;ni<4;ni++){
      #pragma unroll
      for (int r=0;r<4;r++){
        size_t row = bm + wr*64 + mi*16 + g*4 + r;
        size_t col = bn + wc*64 + ni*16 + c16;
        if (OBF) ((u16*)Cv)[row * (size_t)N + col] = f2bf(acc[mi][ni][r]);
        else     ((float*)Cv)[row * (size_t)N + col] = acc[mi][ni][r];
      }
    }
  }
}

// ---------------- RMSNorm + RoPE (q,k only); q pre-scaled by HD^-0.5 * log2(e) ----------------
__global__ __launch_bounds__(256) void k_norm_rope(const u16* __restrict__ qkv, const int* __restrict__ pos,
    const float* __restrict__ qsc, const float* __restrict__ ksc,
    const float* __restrict__ ct, const float* __restrict__ st,
    u16* __restrict__ qo, u16* __restrict__ ko){
  int bs = blockIdx.x;
  int hh = blockIdx.y * 4 + (threadIdx.x >> 6);
  int d = threadIdx.x & 63;
  int b = bs >> 11, s = bs & 2047;
  const u16* row = qkv + (size_t)bs * 3072 + hh * 128;
  u16 r1 = row[d], r2 = row[d + 64];
  float x1 = bf2f(r1), x2 = bf2f(r2);
  float ssq = x1*x1 + x2*x2;
  #pragma unroll
  for (int mm = 1; mm < 64; mm <<= 1) ssq += __shfl_xor(ssq, mm);
  float inv = rsqrtf(ssq * (1.0f/128.0f) + 1e-6f);
  const float* sc = (hh < 16) ? qsc : ksc;
  float y1 = x1 * inv * sc[d];
  float y2 = x2 * inv * sc[d + 64];
  int p = pos[bs];
  float c = ct[p*64 + d], sn = st[p*64 + d];
  float o1 = y1*c - y2*sn;
  float o2 = y2*c + y1*sn;
  if (hh < 16){
    // fold HD^-0.5 * log2(e): softmax runs in log2 domain (exp2)
    o1 *= 0.1275174528f;
    o2 *= 0.1275174528f;
    size_t o = ((size_t)(b*16 + hh) * 2048 + s) * 128 + d;
    qo[o] = f2bf(o1); qo[o + 64] = f2bf(o2);
  } else {
    size_t o = ((size_t)(b*4 + (hh-16)) * 2048 + s) * 128 + d;
    ko[o] = f2bf(o1); ko[o + 64] = f2bf(o2);
  }
}

// ---------------- flash attention: 8-wave PAIRED 128-row q-blocks (256 blocks x 512),
// shuffle-free remapped QK^T (k = 32(nt>>1)+4(nt&1)+8(c16>>2)+(c16&3)), direct pack,
// fused PV sharing V-frag reads between groups, l via ones-MFMA,
// K,V dbuf via global_load_lds, counted vmcnt(4). ----
__device__ __forceinline__ void stage_kv8(int w, int lane, u16* ksb, u16* vsb,
                                          const u16* kp, const u16* vp, int c0){
  #pragma unroll
  for (int p = 0; p < 2; p++){
    int j = (w*2 + p)*64 + lane;
    int r = j >> 4, slot = j & 15;
    int swzr = (r & 3) | ((r >> 1) & 4);
    gload16(kp + (size_t)(c0 + r)*128 + ((slot ^ swzr) << 3),
            (const char*)ksb + (w*2 + p)*1024);
  }
  #pragma unroll
  for (int p = 0; p < 2; p++){
    int j = (w*2 + p)*64 + lane;
    int r = j >> 3, slot = j & 7;
    gload16(vp + (size_t)r*2048 + c0 + ((slot ^ (r & 7)) << 3),
            (const char*)vsb + (w*2 + p)*1024);
  }
}

// causal mask (remapped k) + exp2 + direct pack (no cross-lane ops)
__device__ __forceinline__ void pack_group(f32x4 (&sacc)[4],
    int qrow, bool diag, int c0, int g, u32x4* pw){
  if (diag){
    #pragma unroll
    for (int nt = 0; nt < 4; nt++)
      #pragma unroll
      for (int r = 0; r < 4; r++)
        if (c0 + ((nt >> 1) << 5) + ((nt & 1) << 2) + 8*g + r > qrow)
          sacc[nt][r] = -1e30f;
  }
  #pragma unroll
  for (int nt = 0; nt < 4; nt++)
    #pragma unroll
    for (int r = 0; r < 4; r++)
      sacc[nt][r] = exp2f(sacc[nt][r]);
  #pragma unroll
  for (int kk2 = 0; kk2 < 2; kk2++){
    pw[kk2].x = cvt_pk_bf16(sacc[2*kk2][0],   sacc[2*kk2][1]);
    pw[kk2].y = cvt_pk_bf16(sacc[2*kk2][2],   sacc[2*kk2][3]);
    pw[kk2].z = cvt_pk_bf16(sacc[2*kk2+1][0], sacc[2*kk2+1][1]);
    pw[kk2].w = cvt_pk_bf16(sacc[2*kk2+1][2], sacc[2*kk2+1][3]);
  }
}

__global__ __launch_bounds__(512, 2) void k_attn(const u16* __restrict__ q, const u16* __restrict__ k,
    const u16* __restrict__ vt, u16* __restrict__ attn){
  __shared__ u16 Ks[2][64*128];
  __shared__ u16 Vs[2][128*64];
  int lane = threadIdx.x & 63, w = threadIdx.x >> 6;   // w in 0..7
  int g = lane >> 4, c16 = lane & 15;
  int bid = blockIdx.x;
  int logical = (bid & 7)*32 + (bid >> 3);   // XCD-chunked (256 blocks)
  int pi = logical & 7;
  int hb = logical >> 3;
  int h = hb & 15, b = hb >> 4;
  int kvh = h >> 2;
  int qbA = pi*128, qbB = (15 - pi)*128;     // paired 128-row q-blocks
  int tA = 2*pi + 1;                         // last tile A needs
  int tmax = 31 - 2*pi;                      // last tile B needs
  const u16* qp = q  + ((size_t)(b*16 + h))  * 2048 * 128;
  const u16* kp = k  + ((size_t)(b*4 + kvh)) * 2048 * 128;
  const u16* vp = vt + ((size_t)(b*4 + kvh)) * 128 * 2048;

  int qrA = qbA + w*16 + c16, qrB = qbB + w*16 + c16;
  bf16x8 qfA[4], qfB[4];
  #pragma unroll
  for (int kk = 0; kk < 4; kk++){
    qfA[kk] = *(const bf16x8*)(qp + (size_t)qrA*128 + kk*32 + g*8);
    qfB[kk] = *(const bf16x8*)(qp + (size_t)qrB*128 + kk*32 + g*8);
  }
  asm volatile("s_waitcnt vmcnt(0)" ::: "memory");   // Q drained -> vmcnt counts staging only

  u32x4 onesw = {0x3F803F80u, 0x3F803F80u, 0x3F803F80u, 0x3F803F80u};
  bf16x8 ones = __builtin_bit_cast(bf16x8, onesw);

  int rb = 8*(c16 >> 2) + (c16 & 3);   // lane's remapped base row
  int cs = c16 & 7;                     // lane-constant K read swizzle

  f32x4 zero = {0.f,0.f,0.f,0.f};
  f32x4 oA[8], oB[8];
  #pragma unroll
  for (int i=0;i<8;i++){ oA[i] = zero; oB[i] = zero; }
  f32x4 lA = zero, lB = zero;

  stage_kv8(w, lane, Ks[0], Vs[0], kp, vp, 0);

  for (int t = 0; t <= tmax; t++){
    int c0 = t*64;
    if (t < tmax){
      stage_kv8(w, lane, Ks[(t+1)&1], Vs[(t+1)&1], kp, vp, c0 + 64);
      asm volatile("s_waitcnt vmcnt(4)" ::: "memory");
    } else {
      asm volatile("s_waitcnt vmcnt(0)" ::: "memory");
    }
    __builtin_amdgcn_s_barrier();
    const u16* ksb = Ks[t&1];
    const u16* vsb = Vs[t&1];
    bool Aact = (t <= tA);
    f32x4 sA[4], sB[4];
    #pragma unroll
    for (int i=0;i<4;i++){ sA[i] = zero; sB[i] = zero; }
    __builtin_amdgcn_s_setprio(1);
    if (Aact){
      #pragma unroll
      for (int nt=0;nt<4;nt++){
        int R = ((nt >> 1) << 5) + ((nt & 1) << 2) + rb;   // remapped K row
        #pragma unroll
        for (int kk=0;kk<4;kk++){
          bf16x8 kf = *(const bf16x8*)&ksb[R*128 + (((kk*4 + g) ^ cs) << 3)];
          sB[nt] = mfma16(kf, qfB[kk], sB[nt]);   // shared kf feeds both groups
          sA[nt] = mfma16(kf, qfA[kk], sA[nt]);
        }
      }
    } else {
      #pragma unroll
      for (int nt=0;nt<4;nt++){
        int R = ((nt >> 1) << 5) + ((nt & 1) << 2) + rb;
        #pragma unroll
        for (int kk=0;kk<4;kk++){
          bf16x8 kf = *(const bf16x8*)&ksb[R*128 + (((kk*4 + g) ^ cs) << 3)];
          sB[nt] = mfma16(kf, qfB[kk], sB[nt]);
        }
      }
    }
    __builtin_amdgcn_s_setprio(0);
    u32x4 pwA[2], pwB[2];
    if (Aact) pack_group(sA, qrA, t >= 2*pi,     c0, g, pwA);   // A diag spans t=2pi,2pi+1
    pack_group(sB, qrB, t >= tmax - 1, c0, g, pwB);             // B diag spans last 2 tiles
    // fused PV: load each V-frag ONCE, feed both groups' MFMAs; l via ones-MFMA
    __builtin_amdgcn_s_setprio(1);
    if (Aact){
      #pragma unroll
      for (int kk2 = 0; kk2 < 2; kk2++){
        bf16x8 pfA = __builtin_bit_cast(bf16x8, pwA[kk2]);
        bf16x8 pfB = __builtin_bit_cast(bf16x8, pwB[kk2]);
        lA = mfma16(pfA, ones, lA);
        lB = mfma16(pfB, ones, lB);
        #pragma unroll
        for (int dt = 0; dt < 8; dt++){
          int d = dt*16 + c16;
          bf16x8 vf = *(const bf16x8*)&vsb[d*64 + (((kk2*4 + g) ^ (d & 7)) << 3)];
          oB[dt] = mfma16(pfB, vf, oB[dt]);
          oA[dt] = mfma16(pfA, vf, oA[dt]);
        }
      }
    } else {
      #pragma unroll
      for (int kk2 = 0; kk2 < 2; kk2++){
        bf16x8 pfB = __builtin_bit_cast(bf16x8, pwB[kk2]);
        lB = mfma16(pfB, ones, lB);
        #pragma unroll
        for (int dt = 0; dt < 8; dt++){
          int d = dt*16 + c16;
          bf16x8 vf = *(const bf16x8*)&vsb[d*64 + (((kk2*4 + g) ^ (d & 7)) << 3)];
          oB[dt] = mfma16(pfB, vf, oB[dt]);
        }
      }
    }
    __builtin_amdgcn_s_setprio(0);
    __builtin_amdgcn_sched_barrier(0);
    asm volatile("s_waitcnt lgkmcnt(0)" ::: "memory"); // LDS reads done before buffers recycle
    __builtin_amdgcn_s_barrier();
  }
  // l has the SAME C-layout as o (row q = g*4+r, replicated across c16) -> no shuffles
  float invA[4], invB[4];
  #pragma unroll
  for (int r = 0; r < 4; r++){
    invA[r] = 1.0f / lA[r];
    invB[r] = 1.0f / lB[r];
  }
  #pragma unroll
  for (int dt=0;dt<8;dt++){
    #pragma unroll
    for (int r=0;r<4;r++){
      size_t orA = (size_t)b*2048 + qbA + w*16 + g*4 + r;
      size_t orB = (size_t)b*2048 + qbB + w*16 + g*4 + r;
      attn[orA*2048 + (size_t)h*128 + dt*16 + c16] = f2bf(oA[dt][r] * invA[r]);
      attn[orB*2048 + (size_t)h*128 + dt*16 + c16] = f2bf(oB[dt][r] * invB[r]);
    }
  }
}

extern "C" void kernel_launch(void* const* d_in, const int* in_sizes, int n_in,
                              void* d_out, int out_size, void* d_ws, size_t ws_size,
                              hipStream_t stream){
  const float* hidden    = (const float*)d_in[0];
  const int*   positions = (const int*)d_in[1];
  const float* Wq = (const float*)d_in[2];
  const float* Wk = (const float*)d_in[3];
  const float* Wv = (const float*)d_in[4];
  const float* Wc = (const float*)d_in[5];
  const float* qs = (const float*)d_in[6];
  const float* ks = (const float*)d_in[7];
  float* out = (float*)d_out;
  char* ws = (char*)d_ws;
  float* ct      = (float*)(ws + 0);
  float* st      = (float*)(ws + 524288);
  u16*   hid_bf  = (u16*)(ws + 1048576);
  u16*   attn_bf = hid_bf;                    // reuse (dead after qkv GEMM)
  u16*   wqkv_t  = (u16*)(ws + 17825792);
  u16*   wct     = (u16*)(ws + 30408704);
  u16*   qkv_bf  = (u16*)(ws + 38797312);
  u16*   q_bf    = (u16*)(ws + 63963136);
  u16*   k_bf    = (u16*)(ws + 80740352);
  u16*   vt_bf   = (u16*)(ws + 84934656);

  k_prep<<<18944, 256, 0, stream>>>(hidden, Wq, Wk, Wv, Wc, hid_bf, wqkv_t, wct, ct, st);
  k_gemm_qkv<<<768, 256, 0, stream>>>(hid_bf, wqkv_t, qkv_bf, vt_bf, 2048);
  k_norm_rope<<<dim3(4096, 5), 256, 0, stream>>>(qkv_bf, positions, qs, ks, ct, st, q_bf, k_bf);
  k_attn<<<256, 512, 0, stream>>>(q_bf, k_bf, vt_bf, attn_bf);
  k_gemm<false><<<512, 256, 0, stream>>>(attn_bf, wct, (void*)out, 4096, 2048, 2048, 16);
}

// Round 26
// 193.556 us; speedup vs baseline: 1.0327x; 1.0327x over previous
//
#include <hip/hip_runtime.h>
#include <stdint.h>

typedef unsigned short u16;
typedef unsigned int u32;
typedef __bf16 bf16x8 __attribute__((ext_vector_type(8)));
typedef float f32x4 __attribute__((ext_vector_type(4)));
typedef u32 u32x4 __attribute__((ext_vector_type(4)));

__device__ __forceinline__ u16 f2bf(float x){
  u32 u = __float_as_uint(x);
  u += 0x7FFFu + ((u >> 16) & 1u);
  return (u16)(u >> 16);
}
__device__ __forceinline__ float bf2f(u16 h){
  return __uint_as_float(((u32)h) << 16);
}
__device__ __forceinline__ u32 cvt_pk_bf16(float lo, float hi){
  u32 r;
  asm("v_cvt_pk_bf16_f32 %0, %1, %2" : "=v"(r) : "v"(lo), "v"(hi));
  return r;
}
__device__ __forceinline__ f32x4 mfma16(bf16x8 a, bf16x8 b, f32x4 c){
  return __builtin_amdgcn_mfma_f32_16x16x32_bf16(a, b, c, 0, 0, 0);
}
// async global->LDS, 16B per lane. LDS dest = wave-uniform base + lane*16.
__device__ __forceinline__ void gload16(const void* g, const void* l){
  __builtin_amdgcn_global_load_lds(
      (__attribute__((address_space(1))) void*)(uintptr_t)g,
      (__attribute__((address_space(3))) void*)(u32)(uintptr_t)l,
      16, 0, 0);
}

// ---------------- fused prep: cast | trans_qkv | trans_wc | rope_table ----------------
__global__ __launch_bounds__(256) void k_prep(const float* __restrict__ hidden,
    const float* __restrict__ Wq, const float* __restrict__ Wk, const float* __restrict__ Wv,
    const float* __restrict__ Wc, u16* __restrict__ hid_bf, u16* __restrict__ wqkv_t,
    u16* __restrict__ wct, float* __restrict__ ct, float* __restrict__ st){
  __shared__ float tile[32][33];
  int bid = blockIdx.x;
  int t = threadIdx.x;
  if (bid < 8192){                       // f32 -> bf16 cast of hidden
    int i = (bid * 256 + t) * 4;
    float4 v = *(const float4*)(hidden + i);
    ushort4 o;
    o.x = f2bf(v.x); o.y = f2bf(v.y); o.z = f2bf(v.z); o.w = f2bf(v.w);
    *(ushort4*)(hid_bf + i) = o;
    return;
  }
  if (bid < 8192 + 6144){                // Wq|Wk|Wv transpose+cast -> wqkv_t[n][k]
    int b2 = bid - 8192;
    int nb = (b2 % 96) * 32, kb = (b2 / 96) * 32;
    int tx = t & 31, ty = t >> 5;
    #pragma unroll
    for (int j = 0; j < 4; j++){
      int k = kb + ty + j*8;
      int n = nb + tx;
      float v;
      if (n < 2048)      v = Wq[(size_t)k*2048 + n];
      else if (n < 2560) v = Wk[(size_t)k*512 + (n - 2048)];
      else               v = Wv[(size_t)k*512 + (n - 2560)];
      tile[tx][ty + j*8] = v;
    }
    __syncthreads();
    #pragma unroll
    for (int j = 0; j < 4; j++){
      int n = nb + ty + j*8;
      wqkv_t[(size_t)n*2048 + kb + tx] = f2bf(tile[ty + j*8][tx]);
    }
    return;
  }
  if (bid < 8192 + 6144 + 4096){         // Wc transpose+cast -> wct[n][k]
    int b3 = bid - 8192 - 6144;
    int nb = (b3 % 64) * 32, kb = (b3 / 64) * 32;
    int tx = t & 31, ty = t >> 5;
    #pragma unroll
    for (int j = 0; j < 4; j++){
      tile[tx][ty + j*8] = Wc[(size_t)(kb + ty + j*8)*2048 + nb + tx];
    }
    __syncthreads();
    #pragma unroll
    for (int j = 0; j < 4; j++){
      wct[(size_t)(nb + ty + j*8)*2048 + kb + tx] = f2bf(tile[ty + j*8][tx]);
    }
    return;
  }
  {                                      // RoPE cos/sin table
    int b4 = bid - 8192 - 6144 - 4096;
    int idx = b4 * 256 + t;
    int p = idx >> 6, i = idx & 63;
    float freq = powf(10000.0f, -(float)i / 64.0f);
    float ang = (float)p * freq;
    ct[idx] = cosf(ang);
    st[idx] = sinf(ang);
  }
}

// ------- QKV GEMM: q/k column-blocks (bx<20) -> normal bf16 C-write to qkv;
// v column-blocks (bx>=20) -> fused transpose to vt via staging-LDS reuse.
// K is a RUNTIME arg (prevents full K-loop unroll / I$ blowout). -------
__global__ __launch_bounds__(256) void k_gemm_qkv(const u16* __restrict__ A, const u16* __restrict__ Bt,
    u16* __restrict__ qkv, u16* __restrict__ vt, int K){
  __shared__ u16 lds[16384];   // A0|A1|B0|B1 (4 x 4096 u16); V epilogue reuses as 128x128 tile
  int tid = threadIdx.x;
  int lane = tid & 63, w = tid >> 6;
  int g = lane >> 4, c16 = lane & 15;
  int wr = w >> 1, wc = w & 1;
  int chunk = gridDim.x >> 3;
  int logical = (blockIdx.x & 7) * chunk + (blockIdx.x >> 3);
  int bx = logical % 24, by = logical / 24;
  size_t bm = (size_t)by * 128, bn = (size_t)bx * 128;
  f32x4 zero = {0.f, 0.f, 0.f, 0.f};
  f32x4 acc[4][4];
  #pragma unroll
  for (int i=0;i<4;i++)
    #pragma unroll
    for (int j=0;j<4;j++) acc[i][j] = zero;

  int jj = (w*2)*64 + lane;
  const int nt = K >> 5;
  #pragma unroll
  for (int p = 0; p < 2; p++){
    int j = jj + p*64;
    int r = j >> 2, slot = j & 3;
    gload16(A  + (bm + r)*(size_t)K + slot*8, (const char*)(lds)        + (w*2+p)*1024);
    gload16(Bt + (bn + r)*(size_t)K + slot*8, (const char*)(lds + 8192) + (w*2+p)*1024);
  }
  asm volatile("s_waitcnt vmcnt(0)" ::: "memory");
  __builtin_amdgcn_s_barrier();

  int cur = 0;
  #pragma unroll 1
  for (int t = 0; t < nt; ++t){
    if (t + 1 < nt){
      int k0 = (t + 1) << 5;
      #pragma unroll
      for (int p = 0; p < 2; p++){
        int j = jj + p*64;
        int r = j >> 2, slot = j & 3;
        gload16(A  + (bm + r)*(size_t)K + k0 + slot*8, (const char*)(lds + (cur^1)*4096)        + (w*2+p)*1024);
        gload16(Bt + (bn + r)*(size_t)K + k0 + slot*8, (const char*)(lds + 8192 + (cur^1)*4096) + (w*2+p)*1024);
      }
    }
    const u16* Ac = lds + cur*4096;
    const u16* Bc = lds + 8192 + cur*4096;
    bf16x8 af[4], bfr[4];
    #pragma unroll
    for (int mi=0;mi<4;mi++) af[mi]  = *(const bf16x8*)&Ac[(wr*64 + mi*16 + c16)*32 + g*8];
    #pragma unroll
    for (int ni=0;ni<4;ni++) bfr[ni] = *(const bf16x8*)&Bc[(wc*64 + ni*16 + c16)*32 + g*8];
    #pragma unroll
    for (int mi=0;mi<4;mi++)
      #pragma unroll
      for (int ni=0;ni<4;ni++)
        acc[mi][ni] = mfma16(af[mi], bfr[ni], acc[mi][ni]);
    if (t + 1 < nt){
      asm volatile("s_waitcnt vmcnt(0)" ::: "memory");
      __builtin_amdgcn_s_barrier();
    }
    cur ^= 1;
  }
  if (bx < 20){
    // q/k: normal bf16 C-write into qkv[m][3072] (v columns left unwritten/unused)
    #pragma unroll
    for (int mi=0;mi<4;mi++){
      #pragma unroll
      for (int ni=0;ni<4;ni++){
        #pragma unroll
        for (int r=0;r<4;r++){
          size_t row = bm + wr*64 + mi*16 + g*4 + r;
          size_t col = bn + wc*64 + ni*16 + c16;
          qkv[row * (size_t)3072 + col] = f2bf(acc[mi][ni][r]);
        }
      }
    }
  } else {
    // v: transpose via staging-LDS reuse, coalesced 16B stores to vt[b,kvh,d,s]
    __syncthreads();   // all waves done reading staging LDS
    #pragma unroll
    for (int mi=0;mi<4;mi++)
      #pragma unroll
      for (int ni=0;ni<4;ni++)
        #pragma unroll
        for (int r=0;r<4;r++){
          int row = wr*64 + mi*16 + g*4 + r;
          int col = wc*64 + ni*16 + c16;
          lds[col*128 + row] = f2bf(acc[mi][ni][r]);
        }
    __syncthreads();
    int b = (int)(bm >> 11), s0 = (int)(bm & 2047);
    int kvh = bx - 20;
    u16* dst0 = vt + ((size_t)(b*4 + kvh) * 128) * 2048 + s0;
    #pragma unroll
    for (int i = 0; i < 8; i++){
      int ch = i*256 + tid;        // 0..2047: ALL 16B-chunks of the 128x128 tile
      int d = ch >> 4;
      int off = (ch & 15) * 8;
      uint4 vv = *(uint4*)&lds[d*128 + off];
      *(uint4*)(dst0 + (size_t)d*2048 + off) = vv;
    }
  }
}

// ------- generic GEMM (output proj), T3-min 2-phase pipeline -------
template<bool OBF>
__global__ __launch_bounds__(256) void k_gemm(const u16* __restrict__ A, const u16* __restrict__ Bt,
                                              void* __restrict__ Cv, int M, int N, int K, int nbx){
  __shared__ u16 As[2][128*32], Bs[2][128*32];
  int tid = threadIdx.x;
  int lane = tid & 63, w = tid >> 6;
  int g = lane >> 4, c16 = lane & 15;
  int wr = w >> 1, wc = w & 1;
  int chunk = gridDim.x >> 3;
  int logical = (blockIdx.x & 7) * chunk + (blockIdx.x >> 3);
  int bx = logical % nbx, by = logical / nbx;
  size_t bm = (size_t)by * 128, bn = (size_t)bx * 128;
  f32x4 zero = {0.f, 0.f, 0.f, 0.f};
  f32x4 acc[4][4];
  #pragma unroll
  for (int i=0;i<4;i++)
    #pragma unroll
    for (int j=0;j<4;j++) acc[i][j] = zero;

  int jj = (w*2)*64 + lane;
  int nt = K >> 5;
  #pragma unroll
  for (int p = 0; p < 2; p++){
    int j = jj + p*64;
    int r = j >> 2, slot = j & 3;
    gload16(A  + (bm + r)*(size_t)K + slot*8, (const char*)As[0] + (w*2+p)*1024);
    gload16(Bt + (bn + r)*(size_t)K + slot*8, (const char*)Bs[0] + (w*2+p)*1024);
  }
  asm volatile("s_waitcnt vmcnt(0)" ::: "memory");
  __builtin_amdgcn_s_barrier();

  int cur = 0;
  #pragma unroll 1
  for (int t = 0; t < nt; ++t){
    if (t + 1 < nt){
      int k0 = (t + 1) << 5;
      #pragma unroll
      for (int p = 0; p < 2; p++){
        int j = jj + p*64;
        int r = j >> 2, slot = j & 3;
        gload16(A  + (bm + r)*(size_t)K + k0 + slot*8, (const char*)As[cur^1] + (w*2+p)*1024);
        gload16(Bt + (bn + r)*(size_t)K + k0 + slot*8, (const char*)Bs[cur^1] + (w*2+p)*1024);
      }
    }
    const u16* Ac = As[cur];
    const u16* Bc = Bs[cur];
    bf16x8 af[4], bfr[4];
    #pragma unroll
    for (int mi=0;mi<4;mi++) af[mi]  = *(const bf16x8*)&Ac[(wr*64 + mi*16 + c16)*32 + g*8];
    #pragma unroll
    for (int ni=0;ni<4;ni++) bfr[ni] = *(const bf16x8*)&Bc[(wc*64 + ni*16 + c16)*32 + g*8];
    #pragma unroll
    for (int mi=0;mi<4;mi++)
      #pragma unroll
      for (int ni=0;ni<4;ni++)
        acc[mi][ni] = mfma16(af[mi], bfr[ni], acc[mi][ni]);
    if (t + 1 < nt){
      asm volatile("s_waitcnt vmcnt(0)" ::: "memory");
      __builtin_amdgcn_s_barrier();
    }
    cur ^= 1;
  }
  #pragma unroll
  for (int mi=0;mi<4;mi++){
    #pragma unroll
    for (int ni=0;ni<4;ni++){
      #pragma unroll
      for (int r=0;r<4;r++){
        size_t row = bm + wr*64 + mi*16 + g*4 + r;
        size_t col = bn + wc*64 + ni*16 + c16;
        if (OBF) ((u16*)Cv)[row * (size_t)N + col] = f2bf(acc[mi][ni][r]);
        else     ((float*)Cv)[row * (size_t)N + col] = acc[mi][ni][r];
      }
    }
  }
}

// ---------------- RMSNorm + RoPE (q,k only); q pre-scaled by HD^-0.5 * log2(e) ----------------
__global__ __launch_bounds__(256) void k_norm_rope(const u16* __restrict__ qkv, const int* __restrict__ pos,
    const float* __restrict__ qsc, const float* __restrict__ ksc,
    const float* __restrict__ ct, const float* __restrict__ st,
    u16* __restrict__ qo, u16* __restrict__ ko){
  int bs = blockIdx.x;
  int hh = blockIdx.y * 4 + (threadIdx.x >> 6);
  int d = threadIdx.x & 63;
  int b = bs >> 11, s = bs & 2047;
  const u16* row = qkv + (size_t)bs * 3072 + hh * 128;
  u16 r1 = row[d], r2 = row[d + 64];
  float x1 = bf2f(r1), x2 = bf2f(r2);
  float ssq = x1*x1 + x2*x2;
  #pragma unroll
  for (int mm = 1; mm < 64; mm <<= 1) ssq += __shfl_xor(ssq, mm);
  float inv = rsqrtf(ssq * (1.0f/128.0f) + 1e-6f);
  const float* sc = (hh < 16) ? qsc : ksc;
  float y1 = x1 * inv * sc[d];
  float y2 = x2 * inv * sc[d + 64];
  int p = pos[bs];
  float c = ct[p*64 + d], sn = st[p*64 + d];
  float o1 = y1*c - y2*sn;
  float o2 = y2*c + y1*sn;
  if (hh < 16){
    // fold HD^-0.5 * log2(e): softmax runs in log2 domain (exp2)
    o1 *= 0.1275174528f;
    o2 *= 0.1275174528f;
    size_t o = ((size_t)(b*16 + hh) * 2048 + s) * 128 + d;
    qo[o] = f2bf(o1); qo[o + 64] = f2bf(o2);
  } else {
    size_t o = ((size_t)(b*4 + (hh-16)) * 2048 + s) * 128 + d;
    ko[o] = f2bf(o1); ko[o + 64] = f2bf(o2);
  }
}

// ---------------- flash attention: WAVE-SPLIT pairing (512 blocks x 8 waves),
// swapped QK^T with REMAPPED A-rows: pi_nt(c16) = 32(nt>>1)+4(nt&1)+8(c16>>2)+(c16&3)
// so each lane's S values are exactly its PV A-frag k's -> ZERO cross-lane shuffles.
// K swizzle (r&3)|((r>>1)&4) both sides (read side = c16&7). Static-max log2 softmax,
// l via ones-MFMA, K,V dbuf via global_load_lds, counted vmcnt(4). ----
__device__ __forceinline__ void stage_kv8(int w, int lane, u16* ksb, u16* vsb,
                                          const u16* kp, const u16* vp, int c0){
  #pragma unroll
  for (int p = 0; p < 2; p++){
    int j = (w*2 + p)*64 + lane;
    int r = j >> 4, slot = j & 15;
    int swzr = (r & 3) | ((r >> 1) & 4);
    gload16(kp + (size_t)(c0 + r)*128 + ((slot ^ swzr) << 3),
            (const char*)ksb + (w*2 + p)*1024);
  }
  #pragma unroll
  for (int p = 0; p < 2; p++){
    int j = (w*2 + p)*64 + lane;
    int r = j >> 3, slot = j & 7;
    gload16(vp + (size_t)r*2048 + c0 + ((slot ^ (r & 7)) << 3),
            (const char*)vsb + (w*2 + p)*1024);
  }
}

__global__ __launch_bounds__(512, 2) void k_attn(const u16* __restrict__ q, const u16* __restrict__ k,
    const u16* __restrict__ vt, u16* __restrict__ attn){
  __shared__ u16 Ks[2][64*128];
  __shared__ u16 Vs[2][128*64];
  int lane = threadIdx.x & 63, w = threadIdx.x >> 6;   // w in 0..7
  int g = lane >> 4, c16 = lane & 15;
  int wg = w >> 2;           // 0 = group A (early rows), 1 = group B (late rows)
  int wi = w & 3;
  int bid = blockIdx.x;
  int logical = (bid & 7)*64 + (bid >> 3);   // XCD-chunked (512 blocks)
  int pi = logical & 15;
  int hb = logical >> 4;
  int h = hb & 15, b = hb >> 4;
  int kvh = h >> 2;
  int qb   = wg ? (31 - pi)*64 : pi*64;      // this wave-group's 64-row q-block
  int tact = wg ? (31 - pi)     : pi;        // last tile this group needs (diag there)
  int tmax = 31 - pi;                        // loop bound (B's need >= A's)
  const u16* qp = q  + ((size_t)(b*16 + h))  * 2048 * 128;
  const u16* kp = k  + ((size_t)(b*4 + kvh)) * 2048 * 128;
  const u16* vp = vt + ((size_t)(b*4 + kvh)) * 128 * 2048;

  int qrow = qb + wi*16 + c16;
  bf16x8 qf[4];
  #pragma unroll
  for (int kk = 0; kk < 4; kk++)
    qf[kk] = *(const bf16x8*)(qp + (size_t)qrow*128 + kk*32 + g*8);
  asm volatile("s_waitcnt vmcnt(0)" ::: "memory");   // Q drained -> vmcnt counts staging only

  u32x4 onesw = {0x3F803F80u, 0x3F803F80u, 0x3F803F80u, 0x3F803F80u};
  bf16x8 ones = __builtin_bit_cast(bf16x8, onesw);

  int rb = 8*(c16 >> 2) + (c16 & 3);   // lane's remapped base row
  int cs = c16 & 7;                     // lane-constant K read swizzle

  f32x4 zero = {0.f,0.f,0.f,0.f};
  f32x4 o[8];
  #pragma unroll
  for (int i=0;i<8;i++) o[i] = zero;
  f32x4 l = zero;

  stage_kv8(w, lane, Ks[0], Vs[0], kp, vp, 0);

  for (int t = 0; t <= tmax; t++){
    int c0 = t*64;
    if (t < tmax){
      stage_kv8(w, lane, Ks[(t+1)&1], Vs[(t+1)&1], kp, vp, c0 + 64);
      asm volatile("s_waitcnt vmcnt(4)" ::: "memory");
    } else {
      asm volatile("s_waitcnt vmcnt(0)" ::: "memory");
    }
    __builtin_amdgcn_s_barrier();
    const u16* ksb = Ks[t&1];
    const u16* vsb = Vs[t&1];
    if (t <= tact){
      f32x4 sacc[4];
      #pragma unroll
      for (int i=0;i<4;i++) sacc[i] = zero;
      __builtin_amdgcn_s_setprio(1);
      #pragma unroll
      for (int nt=0;nt<4;nt++){
        int R = ((nt >> 1) << 5) + ((nt & 1) << 2) + rb;   // remapped K row
        #pragma unroll
        for (int kk=0;kk<4;kk++){
          bf16x8 kf = *(const bf16x8*)&ksb[R*128 + (((kk*4 + g) ^ cs) << 3)];
          sacc[nt] = mfma16(kf, qf[kk], sacc[nt]);   // S[k=pi_nt(row)][q]
        }
      }
      __builtin_amdgcn_s_setprio(0);
      // causal mask (remapped k) + exp2 + direct pack (no cross-lane ops)
      if (t == tact){
        #pragma unroll
        for (int nt = 0; nt < 4; nt++)
          #pragma unroll
          for (int r = 0; r < 4; r++)
            if (c0 + ((nt >> 1) << 5) + ((nt & 1) << 2) + 8*g + r > qrow)
              sacc[nt][r] = -1e30f;
      }
      #pragma unroll
      for (int nt = 0; nt < 4; nt++)
        #pragma unroll
        for (int r = 0; r < 4; r++)
          sacc[nt][r] = exp2f(sacc[nt][r]);
      u32x4 pw[2];
      #pragma unroll
      for (int kk2 = 0; kk2 < 2; kk2++){
        pw[kk2].x = cvt_pk_bf16(sacc[2*kk2][0],   sacc[2*kk2][1]);
        pw[kk2].y = cvt_pk_bf16(sacc[2*kk2][2],   sacc[2*kk2][3]);
        pw[kk2].z = cvt_pk_bf16(sacc[2*kk2+1][0], sacc[2*kk2+1][1]);
        pw[kk2].w = cvt_pk_bf16(sacc[2*kk2+1][2], sacc[2*kk2+1][3]);
      }
      __builtin_amdgcn_s_setprio(1);
      #pragma unroll
      for (int kk2 = 0; kk2 < 2; kk2++){
        bf16x8 pf = __builtin_bit_cast(bf16x8, pw[kk2]);
        l = mfma16(pf, ones, l);
        #pragma unroll
        for (int dt = 0; dt < 8; dt++){
          int d = dt*16 + c16;
          bf16x8 vf = *(const bf16x8*)&vsb[d*64 + (((kk2*4 + g) ^ (d & 7)) << 3)];
          o[dt] = mfma16(pf, vf, o[dt]);
        }
      }
      __builtin_amdgcn_s_setprio(0);
    }
    __builtin_amdgcn_sched_barrier(0);
    asm volatile("s_waitcnt lgkmcnt(0)" ::: "memory"); // LDS reads done before buffers recycle
    __builtin_amdgcn_s_barrier();
  }
  // l has the SAME C-layout as o (row q = g*4+r, replicated across c16) -> no shuffles
  float inv[4];
  #pragma unroll
  for (int r = 0; r < 4; r++) inv[r] = 1.0f / l[r];
  #pragma unroll
  for (int dt=0;dt<8;dt++){
    #pragma unroll
    for (int r=0;r<4;r++){
      size_t orow = (size_t)b*2048 + qb + wi*16 + g*4 + r;
      attn[orow*2048 + (size_t)h*128 + dt*16 + c16] = f2bf(o[dt][r] * inv[r]);
    }
  }
}

extern "C" void kernel_launch(void* const* d_in, const int* in_sizes, int n_in,
                              void* d_out, int out_size, void* d_ws, size_t ws_size,
                              hipStream_t stream){
  const float* hidden    = (const float*)d_in[0];
  const int*   positions = (const int*)d_in[1];
  const float* Wq = (const float*)d_in[2];
  const float* Wk = (const float*)d_in[3];
  const float* Wv = (const float*)d_in[4];
  const float* Wc = (const float*)d_in[5];
  const float* qs = (const float*)d_in[6];
  const float* ks = (const float*)d_in[7];
  float* out = (float*)d_out;
  char* ws = (char*)d_ws;
  float* ct      = (float*)(ws + 0);
  float* st      = (float*)(ws + 524288);
  u16*   hid_bf  = (u16*)(ws + 1048576);
  u16*   attn_bf = hid_bf;                    // reuse (dead after qkv GEMM)
  u16*   wqkv_t  = (u16*)(ws + 17825792);
  u16*   wct     = (u16*)(ws + 30408704);
  u16*   qkv_bf  = (u16*)(ws + 38797312);
  u16*   q_bf    = (u16*)(ws + 63963136);
  u16*   k_bf    = (u16*)(ws + 80740352);
  u16*   vt_bf   = (u16*)(ws + 84934656);

  k_prep<<<18944, 256, 0, stream>>>(hidden, Wq, Wk, Wv, Wc, hid_bf, wqkv_t, wct, ct, st);
  k_gemm_qkv<<<768, 256, 0, stream>>>(hid_bf, wqkv_t, qkv_bf, vt_bf, 2048);
  k_norm_rope<<<dim3(4096, 5), 256, 0, stream>>>(qkv_bf, positions, qs, ks, ct, st, q_bf, k_bf);
  k_attn<<<512, 512, 0, stream>>>(q_bf, k_bf, vt_bf, attn_bf);
  k_gemm<false><<<512, 256, 0, stream>>>(attn_bf, wct, (void*)out, 4096, 2048, 2048, 16);
}

// Round 27
// 191.083 us; speedup vs baseline: 1.0461x; 1.0129x over previous
//
#include <hip/hip_runtime.h>
#include <stdint.h>

typedef unsigned short u16;
typedef unsigned int u32;
typedef __bf16 bf16x8 __attribute__((ext_vector_type(8)));
typedef float f32x4 __attribute__((ext_vector_type(4)));
typedef u32 u32x4 __attribute__((ext_vector_type(4)));

__device__ __forceinline__ u16 f2bf(float x){
  u32 u = __float_as_uint(x);
  u += 0x7FFFu + ((u >> 16) & 1u);
  return (u16)(u >> 16);
}
__device__ __forceinline__ float bf2f(u16 h){
  return __uint_as_float(((u32)h) << 16);
}
__device__ __forceinline__ u32 cvt_pk_bf16(float lo, float hi){
  u32 r;
  asm("v_cvt_pk_bf16_f32 %0, %1, %2" : "=v"(r) : "v"(lo), "v"(hi));
  return r;
}
__device__ __forceinline__ f32x4 mfma16(bf16x8 a, bf16x8 b, f32x4 c){
  return __builtin_amdgcn_mfma_f32_16x16x32_bf16(a, b, c, 0, 0, 0);
}
// async global->LDS, 16B per lane. LDS dest = wave-uniform base + lane*16.
__device__ __forceinline__ void gload16(const void* g, const void* l){
  __builtin_amdgcn_global_load_lds(
      (__attribute__((address_space(1))) void*)(uintptr_t)g,
      (__attribute__((address_space(3))) void*)(u32)(uintptr_t)l,
      16, 0, 0);
}

// ---------------- fused prep: cast | trans_qkv | trans_wc | rope_table ----------------
__global__ __launch_bounds__(256) void k_prep(const float* __restrict__ hidden,
    const float* __restrict__ Wq, const float* __restrict__ Wk, const float* __restrict__ Wv,
    const float* __restrict__ Wc, u16* __restrict__ hid_bf, u16* __restrict__ wqkv_t,
    u16* __restrict__ wct, float* __restrict__ ct, float* __restrict__ st){
  __shared__ float tile[32][33];
  int bid = blockIdx.x;
  int t = threadIdx.x;
  if (bid < 8192){                       // f32 -> bf16 cast of hidden
    int i = (bid * 256 + t) * 4;
    float4 v = *(const float4*)(hidden + i);
    ushort4 o;
    o.x = f2bf(v.x); o.y = f2bf(v.y); o.z = f2bf(v.z); o.w = f2bf(v.w);
    *(ushort4*)(hid_bf + i) = o;
    return;
  }
  if (bid < 8192 + 6144){                // Wq|Wk|Wv transpose+cast -> wqkv_t[n][k]
    int b2 = bid - 8192;
    int nb = (b2 % 96) * 32, kb = (b2 / 96) * 32;
    int tx = t & 31, ty = t >> 5;
    #pragma unroll
    for (int j = 0; j < 4; j++){
      int k = kb + ty + j*8;
      int n = nb + tx;
      float v;
      if (n < 2048)      v = Wq[(size_t)k*2048 + n];
      else if (n < 2560) v = Wk[(size_t)k*512 + (n - 2048)];
      else               v = Wv[(size_t)k*512 + (n - 2560)];
      tile[tx][ty + j*8] = v;
    }
    __syncthreads();
    #pragma unroll
    for (int j = 0; j < 4; j++){
      int n = nb + ty + j*8;
      wqkv_t[(size_t)n*2048 + kb + tx] = f2bf(tile[ty + j*8][tx]);
    }
    return;
  }
  if (bid < 8192 + 6144 + 4096){         // Wc transpose+cast -> wct[n][k]
    int b3 = bid - 8192 - 6144;
    int nb = (b3 % 64) * 32, kb = (b3 / 64) * 32;
    int tx = t & 31, ty = t >> 5;
    #pragma unroll
    for (int j = 0; j < 4; j++){
      tile[tx][ty + j*8] = Wc[(size_t)(kb + ty + j*8)*2048 + nb + tx];
    }
    __syncthreads();
    #pragma unroll
    for (int j = 0; j < 4; j++){
      wct[(size_t)(nb + ty + j*8)*2048 + kb + tx] = f2bf(tile[ty + j*8][tx]);
    }
    return;
  }
  {                                      // RoPE cos/sin table
    int b4 = bid - 8192 - 6144 - 4096;
    int idx = b4 * 256 + t;
    int p = idx >> 6, i = idx & 63;
    float freq = powf(10000.0f, -(float)i / 64.0f);
    float ang = (float)p * freq;
    ct[idx] = cosf(ang);
    st[idx] = sinf(ang);
  }
}

// ------- QKV GEMM: q/k column-blocks (bx<20) -> normal bf16 C-write to qkv;
// v column-blocks (bx>=20) -> fused transpose to vt via staging-LDS reuse.
// K is a RUNTIME arg (prevents full K-loop unroll / I$ blowout). -------
__global__ __launch_bounds__(256) void k_gemm_qkv(const u16* __restrict__ A, const u16* __restrict__ Bt,
    u16* __restrict__ qkv, u16* __restrict__ vt, int K){
  __shared__ u16 lds[16384];   // A0|A1|B0|B1 (4 x 4096 u16); V epilogue reuses as 128x128 tile
  int tid = threadIdx.x;
  int lane = tid & 63, w = tid >> 6;
  int g = lane >> 4, c16 = lane & 15;
  int wr = w >> 1, wc = w & 1;
  int chunk = gridDim.x >> 3;
  int logical = (blockIdx.x & 7) * chunk + (blockIdx.x >> 3);
  int bx = logical % 24, by = logical / 24;
  size_t bm = (size_t)by * 128, bn = (size_t)bx * 128;
  f32x4 zero = {0.f, 0.f, 0.f, 0.f};
  f32x4 acc[4][4];
  #pragma unroll
  for (int i=0;i<4;i++)
    #pragma unroll
    for (int j=0;j<4;j++) acc[i][j] = zero;

  int jj = (w*2)*64 + lane;
  const int nt = K >> 5;
  #pragma unroll
  for (int p = 0; p < 2; p++){
    int j = jj + p*64;
    int r = j >> 2, slot = j & 3;
    gload16(A  + (bm + r)*(size_t)K + slot*8, (const char*)(lds)        + (w*2+p)*1024);
    gload16(Bt + (bn + r)*(size_t)K + slot*8, (const char*)(lds + 8192) + (w*2+p)*1024);
  }
  asm volatile("s_waitcnt vmcnt(0)" ::: "memory");
  __builtin_amdgcn_s_barrier();

  int cur = 0;
  #pragma unroll 1
  for (int t = 0; t < nt; ++t){
    if (t + 1 < nt){
      int k0 = (t + 1) << 5;
      #pragma unroll
      for (int p = 0; p < 2; p++){
        int j = jj + p*64;
        int r = j >> 2, slot = j & 3;
        gload16(A  + (bm + r)*(size_t)K + k0 + slot*8, (const char*)(lds + (cur^1)*4096)        + (w*2+p)*1024);
        gload16(Bt + (bn + r)*(size_t)K + k0 + slot*8, (const char*)(lds + 8192 + (cur^1)*4096) + (w*2+p)*1024);
      }
    }
    const u16* Ac = lds + cur*4096;
    const u16* Bc = lds + 8192 + cur*4096;
    bf16x8 af[4], bfr[4];
    #pragma unroll
    for (int mi=0;mi<4;mi++) af[mi]  = *(const bf16x8*)&Ac[(wr*64 + mi*16 + c16)*32 + g*8];
    #pragma unroll
    for (int ni=0;ni<4;ni++) bfr[ni] = *(const bf16x8*)&Bc[(wc*64 + ni*16 + c16)*32 + g*8];
    #pragma unroll
    for (int mi=0;mi<4;mi++)
      #pragma unroll
      for (int ni=0;ni<4;ni++)
        acc[mi][ni] = mfma16(af[mi], bfr[ni], acc[mi][ni]);
    if (t + 1 < nt){
      asm volatile("s_waitcnt vmcnt(0)" ::: "memory");
      __builtin_amdgcn_s_barrier();
    }
    cur ^= 1;
  }
  if (bx < 20){
    // q/k: normal bf16 C-write into qkv[m][3072] (v columns left unwritten/unused)
    #pragma unroll
    for (int mi=0;mi<4;mi++){
      #pragma unroll
      for (int ni=0;ni<4;ni++){
        #pragma unroll
        for (int r=0;r<4;r++){
          size_t row = bm + wr*64 + mi*16 + g*4 + r;
          size_t col = bn + wc*64 + ni*16 + c16;
          qkv[row * (size_t)3072 + col] = f2bf(acc[mi][ni][r]);
        }
      }
    }
  } else {
    // v: transpose via staging-LDS reuse, coalesced 16B stores to vt[b,kvh,d,s]
    __syncthreads();   // all waves done reading staging LDS
    #pragma unroll
    for (int mi=0;mi<4;mi++)
      #pragma unroll
      for (int ni=0;ni<4;ni++)
        #pragma unroll
        for (int r=0;r<4;r++){
          int row = wr*64 + mi*16 + g*4 + r;
          int col = wc*64 + ni*16 + c16;
          lds[col*128 + row] = f2bf(acc[mi][ni][r]);
        }
    __syncthreads();
    int b = (int)(bm >> 11), s0 = (int)(bm & 2047);
    int kvh = bx - 20;
    u16* dst0 = vt + ((size_t)(b*4 + kvh) * 128) * 2048 + s0;
    #pragma unroll
    for (int i = 0; i < 8; i++){
      int ch = i*256 + tid;        // 0..2047: ALL 16B-chunks of the 128x128 tile
      int d = ch >> 4;
      int off = (ch & 15) * 8;
      uint4 vv = *(uint4*)&lds[d*128 + off];
      *(uint4*)(dst0 + (size_t)d*2048 + off) = vv;
    }
  }
}

// ------- generic GEMM (output proj), T3-min 2-phase pipeline -------
template<bool OBF>
__global__ __launch_bounds__(256) void k_gemm(const u16* __restrict__ A, const u16* __restrict__ Bt,
                                              void* __restrict__ Cv, int M, int N, int K, int nbx){
  __shared__ u16 As[2][128*32], Bs[2][128*32];
  int tid = threadIdx.x;
  int lane = tid & 63, w = tid >> 6;
  int g = lane >> 4, c16 = lane & 15;
  int wr = w >> 1, wc = w & 1;
  int chunk = gridDim.x >> 3;
  int logical = (blockIdx.x & 7) * chunk + (blockIdx.x >> 3);
  int bx = logical % nbx, by = logical / nbx;
  size_t bm = (size_t)by * 128, bn = (size_t)bx * 128;
  f32x4 zero = {0.f, 0.f, 0.f, 0.f};
  f32x4 acc[4][4];
  #pragma unroll
  for (int i=0;i<4;i++)
    #pragma unroll
    for (int j=0;j<4;j++) acc[i][j] = zero;

  int jj = (w*2)*64 + lane;
  int nt = K >> 5;
  #pragma unroll
  for (int p = 0; p < 2; p++){
    int j = jj + p*64;
    int r = j >> 2, slot = j & 3;
    gload16(A  + (bm + r)*(size_t)K + slot*8, (const char*)As[0] + (w*2+p)*1024);
    gload16(Bt + (bn + r)*(size_t)K + slot*8, (const char*)Bs[0] + (w*2+p)*1024);
  }
  asm volatile("s_waitcnt vmcnt(0)" ::: "memory");
  __builtin_amdgcn_s_barrier();

  int cur = 0;
  #pragma unroll 1
  for (int t = 0; t < nt; ++t){
    if (t + 1 < nt){
      int k0 = (t + 1) << 5;
      #pragma unroll
      for (int p = 0; p < 2; p++){
        int j = jj + p*64;
        int r = j >> 2, slot = j & 3;
        gload16(A  + (bm + r)*(size_t)K + k0 + slot*8, (const char*)As[cur^1] + (w*2+p)*1024);
        gload16(Bt + (bn + r)*(size_t)K + k0 + slot*8, (const char*)Bs[cur^1] + (w*2+p)*1024);
      }
    }
    const u16* Ac = As[cur];
    const u16* Bc = Bs[cur];
    bf16x8 af[4], bfr[4];
    #pragma unroll
    for (int mi=0;mi<4;mi++) af[mi]  = *(const bf16x8*)&Ac[(wr*64 + mi*16 + c16)*32 + g*8];
    #pragma unroll
    for (int ni=0;ni<4;ni++) bfr[ni] = *(const bf16x8*)&Bc[(wc*64 + ni*16 + c16)*32 + g*8];
    #pragma unroll
    for (int mi=0;mi<4;mi++)
      #pragma unroll
      for (int ni=0;ni<4;ni++)
        acc[mi][ni] = mfma16(af[mi], bfr[ni], acc[mi][ni]);
    if (t + 1 < nt){
      asm volatile("s_waitcnt vmcnt(0)" ::: "memory");
      __builtin_amdgcn_s_barrier();
    }
    cur ^= 1;
  }
  #pragma unroll
  for (int mi=0;mi<4;mi++){
    #pragma unroll
    for (int ni=0;ni<4;ni++){
      #pragma unroll
      for (int r=0;r<4;r++){
        size_t row = bm + wr*64 + mi*16 + g*4 + r;
        size_t col = bn + wc*64 + ni*16 + c16;
        if (OBF) ((u16*)Cv)[row * (size_t)N + col] = f2bf(acc[mi][ni][r]);
        else     ((float*)Cv)[row * (size_t)N + col] = acc[mi][ni][r];
      }
    }
  }
}

// ---------------- RMSNorm + RoPE (q,k), VECTORIZED: 16-lane group per (bs, slot) row,
// 16B loads/stores, partner chunk (d ^ 64) via 4 register shuffles (lane sub^8). ----------------
__global__ __launch_bounds__(256) void k_norm_rope(const u16* __restrict__ qkv, const int* __restrict__ pos,
    const float* __restrict__ qsc, const float* __restrict__ ksc,
    const float* __restrict__ ct, const float* __restrict__ st,
    u16* __restrict__ qo, u16* __restrict__ ko){
  int tid = threadIdx.x;
  int sub = tid & 15;                       // 8-elem chunk index within the 128-col row
  int bs  = blockIdx.x * 16 + (tid >> 4);   // 16 rows per block
  int hh  = blockIdx.y;                     // head slot 0..19
  int b = bs >> 11, s = bs & 2047;
  const u16* row = qkv + (size_t)bs * 3072 + hh * 128 + sub * 8;
  u32x4 v = *(const u32x4*)row;             // 8 bf16
  float x[8];
  #pragma unroll
  for (int j = 0; j < 4; j++){
    x[2*j]   = bf2f((u16)(v[j] & 0xFFFFu));
    x[2*j+1] = bf2f((u16)(v[j] >> 16));
  }
  float ssq = 0.f;
  #pragma unroll
  for (int j = 0; j < 8; j++) ssq += x[j]*x[j];
  ssq += __shfl_xor(ssq, 1);
  ssq += __shfl_xor(ssq, 2);
  ssq += __shfl_xor(ssq, 4);
  ssq += __shfl_xor(ssq, 8);               // full 128-col sum within the 16-lane group
  float inv = rsqrtf(ssq * (1.0f/128.0f) + 1e-6f);
  // RoPE partner chunk (cols d ^ 64) lives at lane sub^8 in the same group
  u32x4 pv;
  #pragma unroll
  for (int j = 0; j < 4; j++) pv[j] = (u32)__shfl_xor((int)v[j], 8);
  float px[8];
  #pragma unroll
  for (int j = 0; j < 4; j++){
    px[2*j]   = bf2f((u16)(pv[j] & 0xFFFFu));
    px[2*j+1] = bf2f((u16)(pv[j] >> 16));
  }
  const float* scp = (hh < 16) ? qsc : ksc;
  float qmul = (hh < 16) ? 0.1275174528f : 1.0f;   // HD^-0.5 * log2(e) folded into q
  int p = pos[bs];
  int ib = (sub & 7) * 8;                   // cos/sin index base (i = d mod 64)
  bool hiHalf = (sub >= 8);
  u16 outv[8];
  #pragma unroll
  for (int j = 0; j < 8; j++){
    float c  = ct[p*64 + ib + j];
    float sn = st[p*64 + ib + j];
    float own = x[j]  * inv * scp[sub*8 + j]     * qmul;
    float oth = px[j] * inv * scp[(sub^8)*8 + j] * qmul;
    float o = hiHalf ? (own*c + oth*sn) : (own*c - oth*sn);
    outv[j] = f2bf(o);
  }
  u32x4 ov;
  #pragma unroll
  for (int j = 0; j < 4; j++) ov[j] = (u32)outv[2*j] | ((u32)outv[2*j+1] << 16);
  if (hh < 16){
    u16* dst = qo + ((size_t)(b*16 + hh) * 2048 + s) * 128 + sub*8;
    *(u32x4*)dst = ov;
  } else {
    u16* dst = ko + ((size_t)(b*4 + (hh-16)) * 2048 + s) * 128 + sub*8;
    *(u32x4*)dst = ov;
  }
}

// ---------------- flash attention: WAVE-SPLIT pairing (512 blocks x 8 waves),
// swapped QK^T with REMAPPED A-rows: pi_nt(c16) = 32(nt>>1)+4(nt&1)+8(c16>>2)+(c16&3)
// so each lane's S values are exactly its PV A-frag k's -> ZERO cross-lane shuffles.
// K swizzle (r&3)|((r>>1)&4) both sides (read side = c16&7). Static-max log2 softmax,
// l via ones-MFMA, K,V dbuf via global_load_lds, counted vmcnt(4). ----
__device__ __forceinline__ void stage_kv8(int w, int lane, u16* ksb, u16* vsb,
                                          const u16* kp, const u16* vp, int c0){
  #pragma unroll
  for (int p = 0; p < 2; p++){
    int j = (w*2 + p)*64 + lane;
    int r = j >> 4, slot = j & 15;
    int swzr = (r & 3) | ((r >> 1) & 4);
    gload16(kp + (size_t)(c0 + r)*128 + ((slot ^ swzr) << 3),
            (const char*)ksb + (w*2 + p)*1024);
  }
  #pragma unroll
  for (int p = 0; p < 2; p++){
    int j = (w*2 + p)*64 + lane;
    int r = j >> 3, slot = j & 7;
    gload16(vp + (size_t)r*2048 + c0 + ((slot ^ (r & 7)) << 3),
            (const char*)vsb + (w*2 + p)*1024);
  }
}

__global__ __launch_bounds__(512, 2) void k_attn(const u16* __restrict__ q, const u16* __restrict__ k,
    const u16* __restrict__ vt, u16* __restrict__ attn){
  __shared__ u16 Ks[2][64*128];
  __shared__ u16 Vs[2][128*64];
  int lane = threadIdx.x & 63, w = threadIdx.x >> 6;   // w in 0..7
  int g = lane >> 4, c16 = lane & 15;
  int wg = w >> 2;           // 0 = group A (early rows), 1 = group B (late rows)
  int wi = w & 3;
  int bid = blockIdx.x;
  int logical = (bid & 7)*64 + (bid >> 3);   // XCD-chunked (512 blocks)
  int pi = logical & 15;
  int hb = logical >> 4;
  int h = hb & 15, b = hb >> 4;
  int kvh = h >> 2;
  int qb   = wg ? (31 - pi)*64 : pi*64;      // this wave-group's 64-row q-block
  int tact = wg ? (31 - pi)     : pi;        // last tile this group needs (diag there)
  int tmax = 31 - pi;                        // loop bound (B's need >= A's)
  const u16* qp = q  + ((size_t)(b*16 + h))  * 2048 * 128;
  const u16* kp = k  + ((size_t)(b*4 + kvh)) * 2048 * 128;
  const u16* vp = vt + ((size_t)(b*4 + kvh)) * 128 * 2048;

  int qrow = qb + wi*16 + c16;
  bf16x8 qf[4];
  #pragma unroll
  for (int kk = 0; kk < 4; kk++)
    qf[kk] = *(const bf16x8*)(qp + (size_t)qrow*128 + kk*32 + g*8);
  asm volatile("s_waitcnt vmcnt(0)" ::: "memory");   // Q drained -> vmcnt counts staging only

  u32x4 onesw = {0x3F803F80u, 0x3F803F80u, 0x3F803F80u, 0x3F803F80u};
  bf16x8 ones = __builtin_bit_cast(bf16x8, onesw);

  int rb = 8*(c16 >> 2) + (c16 & 3);   // lane's remapped base row
  int cs = c16 & 7;                     // lane-constant K read swizzle

  f32x4 zero = {0.f,0.f,0.f,0.f};
  f32x4 o[8];
  #pragma unroll
  for (int i=0;i<8;i++) o[i] = zero;
  f32x4 l = zero;

  stage_kv8(w, lane, Ks[0], Vs[0], kp, vp, 0);

  for (int t = 0; t <= tmax; t++){
    int c0 = t*64;
    if (t < tmax){
      stage_kv8(w, lane, Ks[(t+1)&1], Vs[(t+1)&1], kp, vp, c0 + 64);
      asm volatile("s_waitcnt vmcnt(4)" ::: "memory");
    } else {
      asm volatile("s_waitcnt vmcnt(0)" ::: "memory");
    }
    __builtin_amdgcn_s_barrier();
    const u16* ksb = Ks[t&1];
    const u16* vsb = Vs[t&1];
    if (t <= tact){
      f32x4 sacc[4];
      #pragma unroll
      for (int i=0;i<4;i++) sacc[i] = zero;
      __builtin_amdgcn_s_setprio(1);
      #pragma unroll
      for (int nt=0;nt<4;nt++){
        int R = ((nt >> 1) << 5) + ((nt & 1) << 2) + rb;   // remapped K row
        #pragma unroll
        for (int kk=0;kk<4;kk++){
          bf16x8 kf = *(const bf16x8*)&ksb[R*128 + (((kk*4 + g) ^ cs) << 3)];
          sacc[nt] = mfma16(kf, qf[kk], sacc[nt]);   // S[k=pi_nt(row)][q]
        }
      }
      __builtin_amdgcn_s_setprio(0);
      // causal mask (remapped k) + exp2 + direct pack (no cross-lane ops)
      if (t == tact){
        #pragma unroll
        for (int nt = 0; nt < 4; nt++)
          #pragma unroll
          for (int r = 0; r < 4; r++)
            if (c0 + ((nt >> 1) << 5) + ((nt & 1) << 2) + 8*g + r > qrow)
              sacc[nt][r] = -1e30f;
      }
      #pragma unroll
      for (int nt = 0; nt < 4; nt++)
        #pragma unroll
        for (int r = 0; r < 4; r++)
          sacc[nt][r] = exp2f(sacc[nt][r]);
      u32x4 pw[2];
      #pragma unroll
      for (int kk2 = 0; kk2 < 2; kk2++){
        pw[kk2].x = cvt_pk_bf16(sacc[2*kk2][0],   sacc[2*kk2][1]);
        pw[kk2].y = cvt_pk_bf16(sacc[2*kk2][2],   sacc[2*kk2][3]);
        pw[kk2].z = cvt_pk_bf16(sacc[2*kk2+1][0], sacc[2*kk2+1][1]);
        pw[kk2].w = cvt_pk_bf16(sacc[2*kk2+1][2], sacc[2*kk2+1][3]);
      }
      __builtin_amdgcn_s_setprio(1);
      #pragma unroll
      for (int kk2 = 0; kk2 < 2; kk2++){
        bf16x8 pf = __builtin_bit_cast(bf16x8, pw[kk2]);
        l = mfma16(pf, ones, l);
        #pragma unroll
        for (int dt = 0; dt < 8; dt++){
          int d = dt*16 + c16;
          bf16x8 vf = *(const bf16x8*)&vsb[d*64 + (((kk2*4 + g) ^ (d & 7)) << 3)];
          o[dt] = mfma16(pf, vf, o[dt]);
        }
      }
      __builtin_amdgcn_s_setprio(0);
    }
    __builtin_amdgcn_sched_barrier(0);
    asm volatile("s_waitcnt lgkmcnt(0)" ::: "memory"); // LDS reads done before buffers recycle
    __builtin_amdgcn_s_barrier();
  }
  // l has the SAME C-layout as o (row q = g*4+r, replicated across c16) -> no shuffles
  float inv[4];
  #pragma unroll
  for (int r = 0; r < 4; r++) inv[r] = 1.0f / l[r];
  #pragma unroll
  for (int dt=0;dt<8;dt++){
    #pragma unroll
    for (int r=0;r<4;r++){
      size_t orow = (size_t)b*2048 + qb + wi*16 + g*4 + r;
      attn[orow*2048 + (size_t)h*128 + dt*16 + c16] = f2bf(o[dt][r] * inv[r]);
    }
  }
}

extern "C" void kernel_launch(void* const* d_in, const int* in_sizes, int n_in,
                              void* d_out, int out_size, void* d_ws, size_t ws_size,
                              hipStream_t stream){
  const float* hidden    = (const float*)d_in[0];
  const int*   positions = (const int*)d_in[1];
  const float* Wq = (const float*)d_in[2];
  const float* Wk = (const float*)d_in[3];
  const float* Wv = (const float*)d_in[4];
  const float* Wc = (const float*)d_in[5];
  const float* qs = (const float*)d_in[6];
  const float* ks = (const float*)d_in[7];
  float* out = (float*)d_out;
  char* ws = (char*)d_ws;
  float* ct      = (float*)(ws + 0);
  float* st      = (float*)(ws + 524288);
  u16*   hid_bf  = (u16*)(ws + 1048576);
  u16*   attn_bf = hid_bf;                    // reuse (dead after qkv GEMM)
  u16*   wqkv_t  = (u16*)(ws + 17825792);
  u16*   wct     = (u16*)(ws + 30408704);
  u16*   qkv_bf  = (u16*)(ws + 38797312);
  u16*   q_bf    = (u16*)(ws + 63963136);
  u16*   k_bf    = (u16*)(ws + 80740352);
  u16*   vt_bf   = (u16*)(ws + 84934656);

  k_prep<<<18944, 256, 0, stream>>>(hidden, Wq, Wk, Wv, Wc, hid_bf, wqkv_t, wct, ct, st);
  k_gemm_qkv<<<768, 256, 0, stream>>>(hid_bf, wqkv_t, qkv_bf, vt_bf, 2048);
  k_norm_rope<<<dim3(256, 20), 256, 0, stream>>>(qkv_bf, positions, qs, ks, ct, st, q_bf, k_bf);
  k_attn<<<512, 512, 0, stream>>>(q_bf, k_bf, vt_bf, attn_bf);
  k_gemm<false><<<512, 256, 0, stream>>>(attn_bf, wct, (void*)out, 4096, 2048, 2048, 16);
}